// Round 12
// baseline (5792.813 us; speedup 1.0000x reference)
//
#include <hip/hip_runtime.h>
#include <stdint.h>

// ---------------------------------------------------------------------------
// BiLSTM (2 layers, B=32,T=1024,D=512,H=256) + linear/top2 + LayerNorm + mask
// r12 = r11 with ONE value-exact edit:
//   - k_gemm: double-buffered LDS + single barrier per K-step (T3 2-phase
//     recipe). Same bytes per kk land in alternating buffers, same kk/MFMA
//     order -> bit-identical C (rec inputs untouched).
// k_rec / prep / heads / launch: r11-verbatim (rec is the knife-edge; frozen).
// ---------------------------------------------------------------------------

typedef _Float16 half8 __attribute__((ext_vector_type(8)));
typedef _Float16 half4v __attribute__((ext_vector_type(4)));
typedef float f32x4 __attribute__((ext_vector_type(4)));
typedef unsigned int uint4v __attribute__((ext_vector_type(4)));
typedef unsigned int uint2v __attribute__((ext_vector_type(2)));

#define N_X    (32768*512)
#define N_WIH  (2*2*1024*512)
#define N_WHH  (2*2*1024*256)
#define N_BIAS (2*2*1024)

// direct global->LDS copy, 16B per lane (gfx950)
__device__ __forceinline__ void gload_lds16(const _Float16* g, _Float16* l) {
  __builtin_amdgcn_global_load_lds(
      (const __attribute__((address_space(1))) void*)g,
      (__attribute__((address_space(3))) void*)l, 16, 0, 0);
}

// ---------------------------------------------------------------- prep ------
__global__ __launch_bounds__(256) void k_prep(
    const float* __restrict__ x, const float* __restrict__ wih,
    const float* __restrict__ whh, const float* __restrict__ bih,
    const float* __restrict__ bhh, _Float16* __restrict__ xf,
    _Float16* __restrict__ wihf, _Float16* __restrict__ whhf,
    float* __restrict__ bias)
{
  const int total4 = (N_X + N_WIH + N_WHH + N_BIAS) >> 2;
  for (int i4 = blockIdx.x*256 + threadIdx.x; i4 < total4; i4 += gridDim.x*256) {
    int i = i4 << 2;
    if (i < N_X) {
      f32x4 v = *(const f32x4*)(x + i);
      half4v h;
#pragma unroll
      for (int j = 0; j < 4; ++j) h[j] = (_Float16)v[j];
      *(half4v*)(xf + i) = h;
    } else if (i < N_X + N_WIH) {
      int j0 = i - N_X;
      f32x4 v = *(const f32x4*)(wih + j0);
      half4v h;
#pragma unroll
      for (int j = 0; j < 4; ++j) h[j] = (_Float16)v[j];
      *(half4v*)(wihf + j0) = h;
    } else if (i < N_X + N_WIH + N_WHH) {
      int j0 = i - N_X - N_WIH;
      f32x4 v = *(const f32x4*)(whh + j0);
      half4v h;
#pragma unroll
      for (int j = 0; j < 4; ++j) h[j] = (_Float16)v[j];
      *(half4v*)(whhf + j0) = h;
    } else {
      int j0 = i - N_X - N_WIH - N_WHH;
      f32x4 a = *(const f32x4*)(bih + j0);
      f32x4 b = *(const f32x4*)(bhh + j0);
      f32x4 r;
#pragma unroll
      for (int j = 0; j < 4; ++j) r[j] = a[j] + b[j];
      *(f32x4*)(bias + j0) = r;
    }
  }
}

// ---------------------------------------------------------------- gemm ------
// C[32768][2048] = A[32768][512] @ Bw[2048][512]^T + bias, gate-interleaved C.
// 2-phase pipeline: stage tile k+1 (global_load_lds) BEFORE compute on tile k,
// ONE barrier per K-step (drains stage vmcnt + lgkm). Bit-identical C.
__global__ __launch_bounds__(256) void k_gemm(
    const _Float16* __restrict__ A, const _Float16* __restrict__ Bw,
    const float* __restrict__ bias, _Float16* __restrict__ C)
{
  __shared__ __align__(16) _Float16 As[2][128*32];
  __shared__ __align__(16) _Float16 Bs[2][128*32];
  const int ti = blockIdx.x, tj = blockIdx.y;
  const int tid = threadIdx.x, l = tid & 63, w = tid >> 6;
  const int wm = w >> 1, wn = w & 1;
  f32x4 acc[4][4] = {};

  // prologue: stage kk=0 into buffer 0
#pragma unroll
  for (int p = 0; p < 2; ++p) {
    int idx = p*256 + tid;
    int rr = idx >> 2, c = (idx & 3) * 8;
    gload_lds16(A + (size_t)(ti*128 + rr)*512 + c, As[0] + idx*8);
    gload_lds16(Bw + (size_t)(tj*128 + rr)*512 + c, Bs[0] + idx*8);
  }
  __syncthreads();   // drains vmcnt: buffer 0 ready

  int cur = 0;
  for (int kk = 0; kk < 512; kk += 32) {
    // stage next tile into the other buffer (overlaps with compute below)
    if (kk + 32 < 512) {
#pragma unroll
      for (int p = 0; p < 2; ++p) {
        int idx = p*256 + tid;
        int rr = idx >> 2, c = (idx & 3) * 8;
        gload_lds16(A + (size_t)(ti*128 + rr)*512 + kk + 32 + c, As[cur^1] + idx*8);
        gload_lds16(Bw + (size_t)(tj*128 + rr)*512 + kk + 32 + c, Bs[cur^1] + idx*8);
      }
    }
    // compute on current buffer (fragment layout/order identical to r11)
    half8 af[4], bfr[4];
#pragma unroll
    for (int m = 0; m < 4; ++m)
      af[m] = *(const half8*)(As[cur] + (wm*64 + m*16 + (l&15))*32 + (l>>4)*8);
#pragma unroll
    for (int n = 0; n < 4; ++n)
      bfr[n] = *(const half8*)(Bs[cur] + (wn*64 + n*16 + (l&15))*32 + (l>>4)*8);
#pragma unroll
    for (int m = 0; m < 4; ++m)
#pragma unroll
      for (int n = 0; n < 4; ++n)
        acc[m][n] = __builtin_amdgcn_mfma_f32_16x16x32_f16(af[m], bfr[n], acc[m][n], 0, 0, 0);
    __syncthreads();   // one barrier/K-step: stage drained, buffers safe
    cur ^= 1;
  }

  const int colb = tj*128 + wn*64 + (l & 15);
  const int rowb = ti*128 + wm*64 + ((l >> 4) << 2);
#pragma unroll
  for (int n = 0; n < 4; ++n) {
    int cg = colb + n*16;
    float bv = bias[cg];
    int dirb = cg >> 10, g = (cg >> 8) & 3, col = cg & 255;
    size_t nc = (size_t)dirb*1024 + col*4 + g;
#pragma unroll
    for (int m = 0; m < 4; ++m)
#pragma unroll
      for (int j = 0; j < 4; ++j)
        C[(size_t)(rowb + m*16 + j)*2048 + nc] = (_Float16)(acc[m][n][j] + bv);
  }
}

// ----------------------------------------------------------------- rec ------
__device__ __forceinline__ float sigf(float x) {
  return __fdividef(1.f, 1.f + __expf(-x));
}
__device__ __forceinline__ float tanh_fast(float x) {
  float e = __expf(-2.f * fabsf(x));
  float r = __fdividef(1.f - e, 1.f + e);
  return x < 0.f ? -r : r;
}

// grid = 32 WGs x 512 threads; workers have (bid&7) < 2: dir = bid&7, q = bid>>3.
// Wave w8 = rh*4 + colq: rows [rh*16, rh*16+16), cols [q*64+colq*16, +16).
// flags layout: flags[dir*128 + w8*16 + q] (u32). The 4 WG flags of (dir,w8)
// share one 16B quad -> single dwordx4 poll. xcd posts at flags[1024+wid].
// pub: [2 parity][2 dir][4 q][32][64] fp16 (r3-proven layout).
__global__ __launch_bounds__(512, 2) void k_rec(
    const _Float16* __restrict__ Gx,   // [32768][2048] gate-interleaved
    const _Float16* __restrict__ Whh,  // [2][1024][256]
    const long long* __restrict__ lens_raw,
    _Float16* __restrict__ Hout,       // [32768][512]  pre-zeroed
    _Float16* __restrict__ pub,        // [2 par][2 dir][4 q][32][64]
    unsigned int* __restrict__ flags)
{
  const int bid = blockIdx.x;
  const int sub = bid & 7;
  if (sub >= 2) return;
  const int dir = sub, q = bid >> 3;
  const int wid = dir*4 + q;
  const int tid = threadIdx.x, w8 = tid >> 6, l = tid & 63;
  const int lq = l >> 4;
  const int rh = w8 >> 2;            // row half 0/1
  const int colq = w8 & 3;           // col quarter 0..3
  const int ncl = colq*16 + (l & 15);  // col within WG's 64-col slice

  __shared__ __align__(16) _Float16 hbuf[2*32*256];  // 2 parity x 16KB
  __shared__ int s_fast;
  for (int i = tid; i < 2*32*256; i += 512) hbuf[i] = (_Float16)0.f;

  // ---- XCD placement handshake (once) ----
  int xcc;
  asm volatile("s_getreg_b32 %0, hwreg(HW_REG_XCC_ID)" : "=s"(xcc));
  unsigned int* xcdbuf = flags + 1024;
  if (tid == 0) {
    __hip_atomic_store(&xcdbuf[wid], (unsigned)(xcc + 1),
                       __ATOMIC_RELEASE, __HIP_MEMORY_SCOPE_AGENT);
    unsigned vv[4];
    for (int i = 0; i < 4; ++i) {
      unsigned u;
      do {
        u = __hip_atomic_load(&xcdbuf[dir*4 + i],
                              __ATOMIC_ACQUIRE, __HIP_MEMORY_SCOPE_AGENT);
      } while (u == 0);
      vv[i] = u;
    }
    s_fast = (vv[0]==vv[1] && vv[1]==vv[2] && vv[2]==vv[3]) ? 1 : 0;
  }

  // Whh B-fragments resident in registers: wave's 16 cols, all 4 gates.
  half8 Bf[4][8];
#pragma unroll
  for (int g = 0; g < 4; ++g)
#pragma unroll
    for (int kt = 0; kt < 8; ++kt)
      Bf[g][kt] = *(const half8*)(Whh + ((size_t)dir*1024 + g*256 + q*64 + ncl)*256 + kt*32 + lq*8);

  // activation rows: r(j) = rh*16 + lq*4 + j  (global batch index)
  int mylen[4];
  {
    bool ok64 = true;
    long long tmp[4];
#pragma unroll
    for (int j = 0; j < 4; ++j) {
      long long vv = lens_raw[rh*16 + lq*4 + j];
      tmp[j] = vv;
      ok64 = ok64 && (vv >= 1 && vv <= 1024);
    }
    const int* l32 = (const int*)lens_raw;
#pragma unroll
    for (int j = 0; j < 4; ++j)
      mylen[j] = ok64 ? (int)tmp[j] : l32[rh*16 + lq*4 + j];
  }

  float cst[4] = {};
  half4v gpf[4];

#pragma unroll
  for (int j = 0; j < 4; ++j) {
    int grow = rh*16 + lq*4 + j;
    int t = dir == 0 ? 0 : mylen[j] - 1;
    gpf[j] = *(const half4v*)(Gx + ((size_t)grow*1024 + t)*2048 + dir*1024 + ((q*64 + ncl) << 2));
  }

  // staging: 768 x 16B chunks (3 partners x 32 rows x 8 col-groups).
  // chunk c: i=c>>8 (partner), rr=(c&255)>>3 (row), cg=c&7 (8-half group).
  // thread stages c=tid, and (tid<256) c=tid+512 -> same (rr,cg), partner 2.
  int qp_[3];
#pragma unroll
  for (int i = 0; i < 3; ++i) qp_[i] = i + (i >= q ? 1 : 0);
  const int c1  = tid;
  const int i1  = c1 >> 8;                 // 0 or 1
  const int rr  = (c1 & 255) >> 3;         // 0..31
  const int cg  = c1 & 7;                  // 0..7
  const int w8p = ((c1 & 255) >> 7)*4 + (cg >> 1);   // producer wave
  const int qpa = qp_[i1];
  const int qpb = qp_[2];
  const bool two = (tid < 256);
  // poll quad: 4 WG flags of (dir, w8p)
  const volatile uint4v* fquad =
      (const volatile uint4v*)(flags + dir*128 + w8p*16);
  // LDS dst bytes (XOR swizzle acts on 16B granules -> block copy valid)
  const int dsta = ((rr*512 + (qpa*64 + cg*8)*2) ^ ((rr & 7) << 4));
  const int dstb = ((rr*512 + (qpb*64 + cg*8)*2) ^ ((rr & 7) << 4));

  __syncthreads();
  const bool FAST = (s_fast != 0);

  for (int s = 0; s < 1024; ++s) {
    const int p = s & 1;
    const int pr_base = p * 16384;       // byte offsets into hbuf
    const int pw_base = (p ^ 1) * 16384;

    // gates: acc init from Gx, then 8 kt MFMAs  (r5-verbatim summation order)
    f32x4 acc[4];
#pragma unroll
    for (int g = 0; g < 4; ++g)
#pragma unroll
      for (int j = 0; j < 4; ++j) acc[g][j] = (float)gpf[j][g];

    // prefetch step s+1 (r5-verbatim position + clamped formula)
#pragma unroll
    for (int j = 0; j < 4; ++j) {
      int grow = rh*16 + lq*4 + j;
      int t = dir == 0 ? s + 1 : mylen[j] - 2 - s;
      t = t < 0 ? 0 : (t > 1023 ? 1023 : t);
      gpf[j] = *(const half4v*)(Gx + ((size_t)grow*1024 + t)*2048 + dir*1024 + ((q*64 + ncl) << 2));
    }

    // gates += h(s-1) @ Whh^T  (A rows = wave's 16 batch rows from LDS)
#pragma unroll
    for (int kt = 0; kt < 8; ++kt) {
      int row = rh*16 + (l & 15);
      int byte = pr_base + ((row*512 + kt*64 + lq*16) ^ ((row & 7) << 4));
      half8 a = *(const half8*)((const char*)hbuf + byte);
#pragma unroll
      for (int g = 0; g < 4; ++g)
        acc[g] = __builtin_amdgcn_mfma_f32_16x16x32_f16(a, Bf[g][kt], acc[g], 0, 0, 0);
    }

    // activation: 4 cells; LDS write + pub publish + Hout (r5-verbatim)
    _Float16* mypub = pub + ((size_t)p*8 + wid)*2048;
#pragma unroll
    for (int j = 0; j < 4; ++j) {
      float gi = sigf(acc[0][j]);
      float gf = sigf(acc[1][j]);
      float gg = tanh_fast(acc[2][j]);
      float go = sigf(acc[3][j]);
      float cn = gf*cst[j] + gi*gg;
      cst[j] = cn;
      float hn = go * tanh_fast(cn);
      _Float16 h16 = (_Float16)hn;
      int r = rh*16 + lq*4 + j;
      int colg = q*64 + ncl;
      int byte = pw_base + ((r*512 + colg*2) ^ ((r & 7) << 4));
      *(_Float16*)((char*)hbuf + byte) = h16;   // own slice for next step
      mypub[r*64 + ncl] = h16;                  // publish
      if (s < mylen[j]) {
        int t = dir == 0 ? s : mylen[j] - 1 - s;
        Hout[((size_t)r*1024 + t)*512 + dir*256 + colg] = h16;
      }
    }

    if (FAST) {
      // same-XCD: shared L2 is the coherence point (r5-proven sequence)
      asm volatile("s_waitcnt vmcnt(0)" ::: "memory");
      if (l == 0) flags[dir*128 + w8*16 + q] = (unsigned)(s + 1);  // plain store
      asm volatile("" ::: "memory");
      // poll: ONE volatile dwordx4 covering all 4 WG flags of (dir, w8p)
      int guard = 0;
      unsigned mn;
      do {
        uint4v f = *fquad;
        unsigned a = f[0] < f[1] ? f[0] : f[1];
        unsigned b = f[2] < f[3] ? f[2] : f[3];
        mn = a < b ? a : b;
        if (++guard > (1 << 22)) break;
      } while (mn <= (unsigned)s);
      // stage 16B chunks (volatile = L1-bypass; <=2 serialized round-trips)
      {
        const volatile uint4v* spa =
            (const volatile uint4v*)(pub + ((size_t)p*8 + dir*4 + qpa)*2048 + rr*64 + cg*8);
        uint4v da = *spa;
        *(uint4v*)((char*)hbuf + pw_base + dsta) = da;
        if (two) {
          const volatile uint4v* spb =
              (const volatile uint4v*)(pub + ((size_t)p*8 + dir*4 + qpb)*2048 + rr*64 + cg*8);
          uint4v db = *spb;
          *(uint4v*)((char*)hbuf + pw_base + dstb) = db;
        }
      }
    } else {
      // cross-XCD fallback (r5 fence pattern, new addresses)
      __threadfence();
      if (l == 0)
        __hip_atomic_store(&flags[dir*128 + w8*16 + q], (unsigned)(s + 1),
                           __ATOMIC_RELAXED, __HIP_MEMORY_SCOPE_AGENT);
      unsigned f0, f1, f2;
      int guard = 0;
      const unsigned* fb = flags + dir*128 + w8p*16;
      do {
        f0 = __hip_atomic_load(fb + qp_[0], __ATOMIC_RELAXED, __HIP_MEMORY_SCOPE_AGENT);
        f1 = __hip_atomic_load(fb + qp_[1], __ATOMIC_RELAXED, __HIP_MEMORY_SCOPE_AGENT);
        f2 = __hip_atomic_load(fb + qp_[2], __ATOMIC_RELAXED, __HIP_MEMORY_SCOPE_AGENT);
        if (++guard > (1 << 22)) break;
      } while (f0 <= (unsigned)s || f1 <= (unsigned)s || f2 <= (unsigned)s);
      __threadfence();
      {
        uint4v da = *(const uint4v*)(pub + ((size_t)p*8 + dir*4 + qpa)*2048 + rr*64 + cg*8);
        *(uint4v*)((char*)hbuf + pw_base + dsta) = da;
        if (two) {
          uint4v db = *(const uint4v*)(pub + ((size_t)p*8 + dir*4 + qpb)*2048 + rr*64 + cg*8);
          *(uint4v*)((char*)hbuf + pw_base + dstb) = db;
        }
      }
    }
    __syncthreads();
  }
}

// ---------------------------------------------------------------- head ------
__global__ __launch_bounds__(256) void k_head1(
    const _Float16* __restrict__ H, const float* __restrict__ linW,
    const float* __restrict__ linb, const float* __restrict__ gamma,
    const float* __restrict__ beta, float* __restrict__ lnout,
    float* __restrict__ logits)
{
  const int r = blockIdx.x*4 + (threadIdx.x >> 6);
  const int l = threadIdx.x & 63;
  half8 hv = *(const half8*)(H + (size_t)r*512 + l*8);
  f32x4 wa = *(const f32x4*)(linW + l*8);
  f32x4 wb = *(const f32x4*)(linW + l*8 + 4);
  float x[8], wv[8];
#pragma unroll
  for (int j = 0; j < 8; ++j) x[j] = (float)hv[j];
#pragma unroll
  for (int j = 0; j < 4; ++j) { wv[j] = wa[j]; wv[j+4] = wb[j]; }
  float s1 = 0.f, s2 = 0.f, sd = 0.f;
#pragma unroll
  for (int j = 0; j < 8; ++j) { s1 += x[j]; s2 += x[j]*x[j]; sd += x[j]*wv[j]; }
#pragma unroll
  for (int off = 32; off >= 1; off >>= 1) {
    s1 += __shfl_xor(s1, off);
    s2 += __shfl_xor(s2, off);
    sd += __shfl_xor(sd, off);
  }
  float mu = s1 * (1.f/512.f);
  float var = s2 * (1.f/512.f) - mu*mu;
  var = var < 0.f ? 0.f : var;
  float rstd = rsqrtf(var + 1e-5f);
  f32x4 ga = *(const f32x4*)(gamma + l*8);
  f32x4 gb = *(const f32x4*)(gamma + l*8 + 4);
  f32x4 ba = *(const f32x4*)(beta + l*8);
  f32x4 bb = *(const f32x4*)(beta + l*8 + 4);
  f32x4 oa, ob;
#pragma unroll
  for (int j = 0; j < 4; ++j) {
    oa[j] = (x[j]   - mu)*rstd*ga[j] + ba[j];
    ob[j] = (x[j+4] - mu)*rstd*gb[j] + bb[j];
  }
  *(f32x4*)(lnout + (size_t)r*512 + l*8) = oa;
  *(f32x4*)(lnout + (size_t)r*512 + l*8 + 4) = ob;
  if (l == 0) logits[r] = sd + linb[0];
}

__global__ __launch_bounds__(256) void k_head2(
    const float* __restrict__ logits, const void* __restrict__ maskraw,
    float* __restrict__ outmask)
{
  __shared__ float swv[4];
  __shared__ int   swi[4];
  __shared__ int   sidx[2];
  const int b = blockIdx.x, tid = threadIdx.x;
  const float* lg = logits + b*1024;
  float lv[4]; int ltt[4];
#pragma unroll
  for (int i = 0; i < 4; ++i) { ltt[i] = tid + i*256; lv[i] = lg[ltt[i]]; }
  int excl = -1;
  for (int pass = 0; pass < 2; ++pass) {
    float bv = 3.0e38f; int bi = 1 << 30;
#pragma unroll
    for (int i = 0; i < 4; ++i)
      if (ltt[i] != excl && (lv[i] < bv || (lv[i] == bv && ltt[i] < bi))) { bv = lv[i]; bi = ltt[i]; }
#pragma unroll
    for (int off = 32; off >= 1; off >>= 1) {
      float ov = __shfl_xor(bv, off); int oi = __shfl_xor(bi, off);
      if (ov < bv || (ov == bv && oi < bi)) { bv = ov; bi = oi; }
    }
    if ((tid & 63) == 0) { swv[tid >> 6] = bv; swi[tid >> 6] = bi; }
    __syncthreads();
    if (tid == 0) {
      float fv = swv[0]; int fi = swi[0];
      for (int u = 1; u < 4; ++u)
        if (swv[u] < fv || (swv[u] == fv && swi[u] < fi)) { fv = swv[u]; fi = swi[u]; }
      sidx[pass] = fi;
    }
    __syncthreads();
    excl = sidx[0];
    __syncthreads();
  }
  const int i1 = sidx[0], i2 = sidx[1];
  const unsigned char* mb = (const unsigned char*)maskraw;
  const bool mode8 = mb[1] != 0;
#pragma unroll
  for (int i = 0; i < 4; ++i) {
    int t = tid + i*256;
    bool mv = mode8 ? (mb[b*1024 + t] != 0)
                    : (((const int*)maskraw)[b*1024 + t] != 0);
    outmask[b*1024 + t] = (mv && t != i1 && t != i2) ? 1.f : 0.f;
  }
}

// --------------------------------------------------------------- launch -----
extern "C" void kernel_launch(void* const* d_in, const int* in_sizes, int n_in,
                              void* d_out, int out_size, void* d_ws, size_t ws_size,
                              hipStream_t stream) {
  const float* x      = (const float*)d_in[0];
  const long long* ln = (const long long*)d_in[1];
  const void* maskraw = d_in[3];
  const float* wih    = (const float*)d_in[4];
  const float* whh    = (const float*)d_in[5];
  const float* bih    = (const float*)d_in[6];
  const float* bhh    = (const float*)d_in[7];
  const float* linW   = (const float*)d_in[8];
  const float* linb   = (const float*)d_in[9];
  const float* gamma  = (const float*)d_in[10];
  const float* beta   = (const float*)d_in[11];
  float* out = (float*)d_out;

  char* ws = (char*)d_ws;
  _Float16* Xf   = (_Float16*)(ws + 0);           //  32 MB
  _Float16* Hc0  = (_Float16*)(ws + 33554432);    //  32 MB
  _Float16* Hc1  = (_Float16*)(ws + 67108864);    //  32 MB
  _Float16* Gx   = (_Float16*)(ws + 100663296);   // 128 MB
  _Float16* Wihf = (_Float16*)(ws + 234881024);   //   4 MB
  _Float16* Whhf = (_Float16*)(ws + 239075328);   //   2 MB
  float*    bias = (float*)   (ws + 241172480);   //  16 KB
  _Float16* pub0 = (_Float16*)(ws + 241188864);   //  64 KB
  _Float16* pub1 = (_Float16*)(ws + 241254400);   //  64 KB
  unsigned int* flg = (unsigned int*)(ws + 241319936); // 16 KB (2 x 8KB)
  float*  logits = (float*)   (ws + 241336320);   // 128 KB
  if (ws_size < 241500000) return;

  hipMemsetAsync(Hc0, 0, 33554432, stream);
  hipMemsetAsync(Hc1, 0, 33554432, stream);
  hipMemsetAsync(flg, 0, 16384, stream);

  k_prep<<<4096, 256, 0, stream>>>(x, wih, whh, bih, bhh, Xf, Wihf, Whhf, bias);

  // layer 0
  k_gemm<<<dim3(256, 16), 256, 0, stream>>>(Xf, Wihf, bias, Gx);
  k_rec<<<32, 512, 0, stream>>>(Gx, Whhf, ln, Hc0, pub0, flg);
  // layer 1
  k_gemm<<<dim3(256, 16), 256, 0, stream>>>(Hc0, Wihf + 2*1024*512, bias + 2048, Gx);
  k_rec<<<32, 512, 0, stream>>>(Gx, Whhf + 2*1024*256, ln, Hc1, pub1, flg + 2048);

  k_head1<<<8192, 256, 0, stream>>>(Hc1, linW, linb, gamma, beta, out, logits);
  k_head2<<<32, 256, 0, stream>>>(logits, maskraw, out + 16777216);
}

// Round 13
// 5767.470 us; speedup vs baseline: 1.0044x; 1.0044x over previous
//
#include <hip/hip_runtime.h>
#include <stdint.h>

// ---------------------------------------------------------------------------
// BiLSTM (2 layers, B=32,T=1024,D=512,H=256) + linear/top2 + LayerNorm + mask
// r13 = r12 with ONE value-exact edit:
//   - k_rec: s_setprio(1) around the compute phase (acc init, Gx prefetch
//     issue, MFMA, activation); prio 0 during drain/flag/poll/stage. Pure
//     scheduler hint -> bit-identical results; helps the compute wave win
//     issue arbitration over its SIMD-mate spinning on the volatile poll.
// k_rec protocol / prep / gemm / heads / launch otherwise r12-verbatim.
// ---------------------------------------------------------------------------

typedef _Float16 half8 __attribute__((ext_vector_type(8)));
typedef _Float16 half4v __attribute__((ext_vector_type(4)));
typedef float f32x4 __attribute__((ext_vector_type(4)));
typedef unsigned int uint4v __attribute__((ext_vector_type(4)));
typedef unsigned int uint2v __attribute__((ext_vector_type(2)));

#define N_X    (32768*512)
#define N_WIH  (2*2*1024*512)
#define N_WHH  (2*2*1024*256)
#define N_BIAS (2*2*1024)

// direct global->LDS copy, 16B per lane (gfx950)
__device__ __forceinline__ void gload_lds16(const _Float16* g, _Float16* l) {
  __builtin_amdgcn_global_load_lds(
      (const __attribute__((address_space(1))) void*)g,
      (__attribute__((address_space(3))) void*)l, 16, 0, 0);
}

// ---------------------------------------------------------------- prep ------
__global__ __launch_bounds__(256) void k_prep(
    const float* __restrict__ x, const float* __restrict__ wih,
    const float* __restrict__ whh, const float* __restrict__ bih,
    const float* __restrict__ bhh, _Float16* __restrict__ xf,
    _Float16* __restrict__ wihf, _Float16* __restrict__ whhf,
    float* __restrict__ bias)
{
  const int total4 = (N_X + N_WIH + N_WHH + N_BIAS) >> 2;
  for (int i4 = blockIdx.x*256 + threadIdx.x; i4 < total4; i4 += gridDim.x*256) {
    int i = i4 << 2;
    if (i < N_X) {
      f32x4 v = *(const f32x4*)(x + i);
      half4v h;
#pragma unroll
      for (int j = 0; j < 4; ++j) h[j] = (_Float16)v[j];
      *(half4v*)(xf + i) = h;
    } else if (i < N_X + N_WIH) {
      int j0 = i - N_X;
      f32x4 v = *(const f32x4*)(wih + j0);
      half4v h;
#pragma unroll
      for (int j = 0; j < 4; ++j) h[j] = (_Float16)v[j];
      *(half4v*)(wihf + j0) = h;
    } else if (i < N_X + N_WIH + N_WHH) {
      int j0 = i - N_X - N_WIH;
      f32x4 v = *(const f32x4*)(whh + j0);
      half4v h;
#pragma unroll
      for (int j = 0; j < 4; ++j) h[j] = (_Float16)v[j];
      *(half4v*)(whhf + j0) = h;
    } else {
      int j0 = i - N_X - N_WIH - N_WHH;
      f32x4 a = *(const f32x4*)(bih + j0);
      f32x4 b = *(const f32x4*)(bhh + j0);
      f32x4 r;
#pragma unroll
      for (int j = 0; j < 4; ++j) r[j] = a[j] + b[j];
      *(f32x4*)(bias + j0) = r;
    }
  }
}

// ---------------------------------------------------------------- gemm ------
// C[32768][2048] = A[32768][512] @ Bw[2048][512]^T + bias, gate-interleaved C.
// 2-phase pipeline: stage tile k+1 (global_load_lds) BEFORE compute on tile k,
// ONE barrier per K-step (drains stage vmcnt + lgkm). Bit-identical C.
__global__ __launch_bounds__(256) void k_gemm(
    const _Float16* __restrict__ A, const _Float16* __restrict__ Bw,
    const float* __restrict__ bias, _Float16* __restrict__ C)
{
  __shared__ __align__(16) _Float16 As[2][128*32];
  __shared__ __align__(16) _Float16 Bs[2][128*32];
  const int ti = blockIdx.x, tj = blockIdx.y;
  const int tid = threadIdx.x, l = tid & 63, w = tid >> 6;
  const int wm = w >> 1, wn = w & 1;
  f32x4 acc[4][4] = {};

  // prologue: stage kk=0 into buffer 0
#pragma unroll
  for (int p = 0; p < 2; ++p) {
    int idx = p*256 + tid;
    int rr = idx >> 2, c = (idx & 3) * 8;
    gload_lds16(A + (size_t)(ti*128 + rr)*512 + c, As[0] + idx*8);
    gload_lds16(Bw + (size_t)(tj*128 + rr)*512 + c, Bs[0] + idx*8);
  }
  __syncthreads();   // drains vmcnt: buffer 0 ready

  int cur = 0;
  for (int kk = 0; kk < 512; kk += 32) {
    // stage next tile into the other buffer (overlaps with compute below)
    if (kk + 32 < 512) {
#pragma unroll
      for (int p = 0; p < 2; ++p) {
        int idx = p*256 + tid;
        int rr = idx >> 2, c = (idx & 3) * 8;
        gload_lds16(A + (size_t)(ti*128 + rr)*512 + kk + 32 + c, As[cur^1] + idx*8);
        gload_lds16(Bw + (size_t)(tj*128 + rr)*512 + kk + 32 + c, Bs[cur^1] + idx*8);
      }
    }
    // compute on current buffer (fragment layout/order identical to r11)
    half8 af[4], bfr[4];
#pragma unroll
    for (int m = 0; m < 4; ++m)
      af[m] = *(const half8*)(As[cur] + (wm*64 + m*16 + (l&15))*32 + (l>>4)*8);
#pragma unroll
    for (int n = 0; n < 4; ++n)
      bfr[n] = *(const half8*)(Bs[cur] + (wn*64 + n*16 + (l&15))*32 + (l>>4)*8);
#pragma unroll
    for (int m = 0; m < 4; ++m)
#pragma unroll
      for (int n = 0; n < 4; ++n)
        acc[m][n] = __builtin_amdgcn_mfma_f32_16x16x32_f16(af[m], bfr[n], acc[m][n], 0, 0, 0);
    __syncthreads();   // one barrier/K-step: stage drained, buffers safe
    cur ^= 1;
  }

  const int colb = tj*128 + wn*64 + (l & 15);
  const int rowb = ti*128 + wm*64 + ((l >> 4) << 2);
#pragma unroll
  for (int n = 0; n < 4; ++n) {
    int cg = colb + n*16;
    float bv = bias[cg];
    int dirb = cg >> 10, g = (cg >> 8) & 3, col = cg & 255;
    size_t nc = (size_t)dirb*1024 + col*4 + g;
#pragma unroll
    for (int m = 0; m < 4; ++m)
#pragma unroll
      for (int j = 0; j < 4; ++j)
        C[(size_t)(rowb + m*16 + j)*2048 + nc] = (_Float16)(acc[m][n][j] + bv);
  }
}

// ----------------------------------------------------------------- rec ------
__device__ __forceinline__ float sigf(float x) {
  return __fdividef(1.f, 1.f + __expf(-x));
}
__device__ __forceinline__ float tanh_fast(float x) {
  float e = __expf(-2.f * fabsf(x));
  float r = __fdividef(1.f - e, 1.f + e);
  return x < 0.f ? -r : r;
}

// grid = 32 WGs x 512 threads; workers have (bid&7) < 2: dir = bid&7, q = bid>>3.
// Wave w8 = rh*4 + colq: rows [rh*16, rh*16+16), cols [q*64+colq*16, +16).
// flags layout: flags[dir*128 + w8*16 + q] (u32). The 4 WG flags of (dir,w8)
// share one 16B quad -> single dwordx4 poll. xcd posts at flags[1024+wid].
// pub: [2 parity][2 dir][4 q][32][64] fp16 (r3-proven layout).
__global__ __launch_bounds__(512, 2) void k_rec(
    const _Float16* __restrict__ Gx,   // [32768][2048] gate-interleaved
    const _Float16* __restrict__ Whh,  // [2][1024][256]
    const long long* __restrict__ lens_raw,
    _Float16* __restrict__ Hout,       // [32768][512]  pre-zeroed
    _Float16* __restrict__ pub,        // [2 par][2 dir][4 q][32][64]
    unsigned int* __restrict__ flags)
{
  const int bid = blockIdx.x;
  const int sub = bid & 7;
  if (sub >= 2) return;
  const int dir = sub, q = bid >> 3;
  const int wid = dir*4 + q;
  const int tid = threadIdx.x, w8 = tid >> 6, l = tid & 63;
  const int lq = l >> 4;
  const int rh = w8 >> 2;            // row half 0/1
  const int colq = w8 & 3;           // col quarter 0..3
  const int ncl = colq*16 + (l & 15);  // col within WG's 64-col slice

  __shared__ __align__(16) _Float16 hbuf[2*32*256];  // 2 parity x 16KB
  __shared__ int s_fast;
  for (int i = tid; i < 2*32*256; i += 512) hbuf[i] = (_Float16)0.f;

  // ---- XCD placement handshake (once) ----
  int xcc;
  asm volatile("s_getreg_b32 %0, hwreg(HW_REG_XCC_ID)" : "=s"(xcc));
  unsigned int* xcdbuf = flags + 1024;
  if (tid == 0) {
    __hip_atomic_store(&xcdbuf[wid], (unsigned)(xcc + 1),
                       __ATOMIC_RELEASE, __HIP_MEMORY_SCOPE_AGENT);
    unsigned vv[4];
    for (int i = 0; i < 4; ++i) {
      unsigned u;
      do {
        u = __hip_atomic_load(&xcdbuf[dir*4 + i],
                              __ATOMIC_ACQUIRE, __HIP_MEMORY_SCOPE_AGENT);
      } while (u == 0);
      vv[i] = u;
    }
    s_fast = (vv[0]==vv[1] && vv[1]==vv[2] && vv[2]==vv[3]) ? 1 : 0;
  }

  // Whh B-fragments resident in registers: wave's 16 cols, all 4 gates.
  half8 Bf[4][8];
#pragma unroll
  for (int g = 0; g < 4; ++g)
#pragma unroll
    for (int kt = 0; kt < 8; ++kt)
      Bf[g][kt] = *(const half8*)(Whh + ((size_t)dir*1024 + g*256 + q*64 + ncl)*256 + kt*32 + lq*8);

  // activation rows: r(j) = rh*16 + lq*4 + j  (global batch index)
  int mylen[4];
  {
    bool ok64 = true;
    long long tmp[4];
#pragma unroll
    for (int j = 0; j < 4; ++j) {
      long long vv = lens_raw[rh*16 + lq*4 + j];
      tmp[j] = vv;
      ok64 = ok64 && (vv >= 1 && vv <= 1024);
    }
    const int* l32 = (const int*)lens_raw;
#pragma unroll
    for (int j = 0; j < 4; ++j)
      mylen[j] = ok64 ? (int)tmp[j] : l32[rh*16 + lq*4 + j];
  }

  float cst[4] = {};
  half4v gpf[4];

#pragma unroll
  for (int j = 0; j < 4; ++j) {
    int grow = rh*16 + lq*4 + j;
    int t = dir == 0 ? 0 : mylen[j] - 1;
    gpf[j] = *(const half4v*)(Gx + ((size_t)grow*1024 + t)*2048 + dir*1024 + ((q*64 + ncl) << 2));
  }

  // staging: 768 x 16B chunks (3 partners x 32 rows x 8 col-groups).
  // chunk c: i=c>>8 (partner), rr=(c&255)>>3 (row), cg=c&7 (8-half group).
  // thread stages c=tid, and (tid<256) c=tid+512 -> same (rr,cg), partner 2.
  int qp_[3];
#pragma unroll
  for (int i = 0; i < 3; ++i) qp_[i] = i + (i >= q ? 1 : 0);
  const int c1  = tid;
  const int i1  = c1 >> 8;                 // 0 or 1
  const int rr  = (c1 & 255) >> 3;         // 0..31
  const int cg  = c1 & 7;                  // 0..7
  const int w8p = ((c1 & 255) >> 7)*4 + (cg >> 1);   // producer wave
  const int qpa = qp_[i1];
  const int qpb = qp_[2];
  const bool two = (tid < 256);
  // poll quad: 4 WG flags of (dir, w8p)
  const volatile uint4v* fquad =
      (const volatile uint4v*)(flags + dir*128 + w8p*16);
  // LDS dst bytes (XOR swizzle acts on 16B granules -> block copy valid)
  const int dsta = ((rr*512 + (qpa*64 + cg*8)*2) ^ ((rr & 7) << 4));
  const int dstb = ((rr*512 + (qpb*64 + cg*8)*2) ^ ((rr & 7) << 4));

  __syncthreads();
  const bool FAST = (s_fast != 0);

  for (int s = 0; s < 1024; ++s) {
    const int p = s & 1;
    const int pr_base = p * 16384;       // byte offsets into hbuf
    const int pw_base = (p ^ 1) * 16384;

    // ---- compute phase at elevated priority (pure scheduler hint) ----
    __builtin_amdgcn_s_setprio(1);

    // gates: acc init from Gx, then 8 kt MFMAs  (r5-verbatim summation order)
    f32x4 acc[4];
#pragma unroll
    for (int g = 0; g < 4; ++g)
#pragma unroll
      for (int j = 0; j < 4; ++j) acc[g][j] = (float)gpf[j][g];

    // prefetch step s+1 (r5-verbatim position + clamped formula)
#pragma unroll
    for (int j = 0; j < 4; ++j) {
      int grow = rh*16 + lq*4 + j;
      int t = dir == 0 ? s + 1 : mylen[j] - 2 - s;
      t = t < 0 ? 0 : (t > 1023 ? 1023 : t);
      gpf[j] = *(const half4v*)(Gx + ((size_t)grow*1024 + t)*2048 + dir*1024 + ((q*64 + ncl) << 2));
    }

    // gates += h(s-1) @ Whh^T  (A rows = wave's 16 batch rows from LDS)
#pragma unroll
    for (int kt = 0; kt < 8; ++kt) {
      int row = rh*16 + (l & 15);
      int byte = pr_base + ((row*512 + kt*64 + lq*16) ^ ((row & 7) << 4));
      half8 a = *(const half8*)((const char*)hbuf + byte);
#pragma unroll
      for (int g = 0; g < 4; ++g)
        acc[g] = __builtin_amdgcn_mfma_f32_16x16x32_f16(a, Bf[g][kt], acc[g], 0, 0, 0);
    }

    // activation: 4 cells; LDS write + pub publish + Hout (r5-verbatim)
    _Float16* mypub = pub + ((size_t)p*8 + wid)*2048;
#pragma unroll
    for (int j = 0; j < 4; ++j) {
      float gi = sigf(acc[0][j]);
      float gf = sigf(acc[1][j]);
      float gg = tanh_fast(acc[2][j]);
      float go = sigf(acc[3][j]);
      float cn = gf*cst[j] + gi*gg;
      cst[j] = cn;
      float hn = go * tanh_fast(cn);
      _Float16 h16 = (_Float16)hn;
      int r = rh*16 + lq*4 + j;
      int colg = q*64 + ncl;
      int byte = pw_base + ((r*512 + colg*2) ^ ((r & 7) << 4));
      *(_Float16*)((char*)hbuf + byte) = h16;   // own slice for next step
      mypub[r*64 + ncl] = h16;                  // publish
      if (s < mylen[j]) {
        int t = dir == 0 ? s : mylen[j] - 1 - s;
        Hout[((size_t)r*1024 + t)*512 + dir*256 + colg] = h16;
      }
    }

    __builtin_amdgcn_s_setprio(0);   // drain/flag/poll/stage at normal prio

    if (FAST) {
      // same-XCD: shared L2 is the coherence point (r5-proven sequence)
      asm volatile("s_waitcnt vmcnt(0)" ::: "memory");
      if (l == 0) flags[dir*128 + w8*16 + q] = (unsigned)(s + 1);  // plain store
      asm volatile("" ::: "memory");
      // poll: ONE volatile dwordx4 covering all 4 WG flags of (dir, w8p)
      int guard = 0;
      unsigned mn;
      do {
        uint4v f = *fquad;
        unsigned a = f[0] < f[1] ? f[0] : f[1];
        unsigned b = f[2] < f[3] ? f[2] : f[3];
        mn = a < b ? a : b;
        if (++guard > (1 << 22)) break;
      } while (mn <= (unsigned)s);
      // stage 16B chunks (volatile = L1-bypass; <=2 serialized round-trips)
      {
        const volatile uint4v* spa =
            (const volatile uint4v*)(pub + ((size_t)p*8 + dir*4 + qpa)*2048 + rr*64 + cg*8);
        uint4v da = *spa;
        *(uint4v*)((char*)hbuf + pw_base + dsta) = da;
        if (two) {
          const volatile uint4v* spb =
              (const volatile uint4v*)(pub + ((size_t)p*8 + dir*4 + qpb)*2048 + rr*64 + cg*8);
          uint4v db = *spb;
          *(uint4v*)((char*)hbuf + pw_base + dstb) = db;
        }
      }
    } else {
      // cross-XCD fallback (r5 fence pattern, new addresses)
      __threadfence();
      if (l == 0)
        __hip_atomic_store(&flags[dir*128 + w8*16 + q], (unsigned)(s + 1),
                           __ATOMIC_RELAXED, __HIP_MEMORY_SCOPE_AGENT);
      unsigned f0, f1, f2;
      int guard = 0;
      const unsigned* fb = flags + dir*128 + w8p*16;
      do {
        f0 = __hip_atomic_load(fb + qp_[0], __ATOMIC_RELAXED, __HIP_MEMORY_SCOPE_AGENT);
        f1 = __hip_atomic_load(fb + qp_[1], __ATOMIC_RELAXED, __HIP_MEMORY_SCOPE_AGENT);
        f2 = __hip_atomic_load(fb + qp_[2], __ATOMIC_RELAXED, __HIP_MEMORY_SCOPE_AGENT);
        if (++guard > (1 << 22)) break;
      } while (f0 <= (unsigned)s || f1 <= (unsigned)s || f2 <= (unsigned)s);
      __threadfence();
      {
        uint4v da = *(const uint4v*)(pub + ((size_t)p*8 + dir*4 + qpa)*2048 + rr*64 + cg*8);
        *(uint4v*)((char*)hbuf + pw_base + dsta) = da;
        if (two) {
          uint4v db = *(const uint4v*)(pub + ((size_t)p*8 + dir*4 + qpb)*2048 + rr*64 + cg*8);
          *(uint4v*)((char*)hbuf + pw_base + dstb) = db;
        }
      }
    }
    __syncthreads();
  }
}

// ---------------------------------------------------------------- head ------
__global__ __launch_bounds__(256) void k_head1(
    const _Float16* __restrict__ H, const float* __restrict__ linW,
    const float* __restrict__ linb, const float* __restrict__ gamma,
    const float* __restrict__ beta, float* __restrict__ lnout,
    float* __restrict__ logits)
{
  const int r = blockIdx.x*4 + (threadIdx.x >> 6);
  const int l = threadIdx.x & 63;
  half8 hv = *(const half8*)(H + (size_t)r*512 + l*8);
  f32x4 wa = *(const f32x4*)(linW + l*8);
  f32x4 wb = *(const f32x4*)(linW + l*8 + 4);
  float x[8], wv[8];
#pragma unroll
  for (int j = 0; j < 8; ++j) x[j] = (float)hv[j];
#pragma unroll
  for (int j = 0; j < 4; ++j) { wv[j] = wa[j]; wv[j+4] = wb[j]; }
  float s1 = 0.f, s2 = 0.f, sd = 0.f;
#pragma unroll
  for (int j = 0; j < 8; ++j) { s1 += x[j]; s2 += x[j]*x[j]; sd += x[j]*wv[j]; }
#pragma unroll
  for (int off = 32; off >= 1; off >>= 1) {
    s1 += __shfl_xor(s1, off);
    s2 += __shfl_xor(s2, off);
    sd += __shfl_xor(sd, off);
  }
  float mu = s1 * (1.f/512.f);
  float var = s2 * (1.f/512.f) - mu*mu;
  var = var < 0.f ? 0.f : var;
  float rstd = rsqrtf(var + 1e-5f);
  f32x4 ga = *(const f32x4*)(gamma + l*8);
  f32x4 gb = *(const f32x4*)(gamma + l*8 + 4);
  f32x4 ba = *(const f32x4*)(beta + l*8);
  f32x4 bb = *(const f32x4*)(beta + l*8 + 4);
  f32x4 oa, ob;
#pragma unroll
  for (int j = 0; j < 4; ++j) {
    oa[j] = (x[j]   - mu)*rstd*ga[j] + ba[j];
    ob[j] = (x[j+4] - mu)*rstd*gb[j] + bb[j];
  }
  *(f32x4*)(lnout + (size_t)r*512 + l*8) = oa;
  *(f32x4*)(lnout + (size_t)r*512 + l*8 + 4) = ob;
  if (l == 0) logits[r] = sd + linb[0];
}

__global__ __launch_bounds__(256) void k_head2(
    const float* __restrict__ logits, const void* __restrict__ maskraw,
    float* __restrict__ outmask)
{
  __shared__ float swv[4];
  __shared__ int   swi[4];
  __shared__ int   sidx[2];
  const int b = blockIdx.x, tid = threadIdx.x;
  const float* lg = logits + b*1024;
  float lv[4]; int ltt[4];
#pragma unroll
  for (int i = 0; i < 4; ++i) { ltt[i] = tid + i*256; lv[i] = lg[ltt[i]]; }
  int excl = -1;
  for (int pass = 0; pass < 2; ++pass) {
    float bv = 3.0e38f; int bi = 1 << 30;
#pragma unroll
    for (int i = 0; i < 4; ++i)
      if (ltt[i] != excl && (lv[i] < bv || (lv[i] == bv && ltt[i] < bi))) { bv = lv[i]; bi = ltt[i]; }
#pragma unroll
    for (int off = 32; off >= 1; off >>= 1) {
      float ov = __shfl_xor(bv, off); int oi = __shfl_xor(bi, off);
      if (ov < bv || (ov == bv && oi < bi)) { bv = ov; bi = oi; }
    }
    if ((tid & 63) == 0) { swv[tid >> 6] = bv; swi[tid >> 6] = bi; }
    __syncthreads();
    if (tid == 0) {
      float fv = swv[0]; int fi = swi[0];
      for (int u = 1; u < 4; ++u)
        if (swv[u] < fv || (swv[u] == fv && swi[u] < fi)) { fv = swv[u]; fi = swi[u]; }
      sidx[pass] = fi;
    }
    __syncthreads();
    excl = sidx[0];
    __syncthreads();
  }
  const int i1 = sidx[0], i2 = sidx[1];
  const unsigned char* mb = (const unsigned char*)maskraw;
  const bool mode8 = mb[1] != 0;
#pragma unroll
  for (int i = 0; i < 4; ++i) {
    int t = tid + i*256;
    bool mv = mode8 ? (mb[b*1024 + t] != 0)
                    : (((const int*)maskraw)[b*1024 + t] != 0);
    outmask[b*1024 + t] = (mv && t != i1 && t != i2) ? 1.f : 0.f;
  }
}

// --------------------------------------------------------------- launch -----
extern "C" void kernel_launch(void* const* d_in, const int* in_sizes, int n_in,
                              void* d_out, int out_size, void* d_ws, size_t ws_size,
                              hipStream_t stream) {
  const float* x      = (const float*)d_in[0];
  const long long* ln = (const long long*)d_in[1];
  const void* maskraw = d_in[3];
  const float* wih    = (const float*)d_in[4];
  const float* whh    = (const float*)d_in[5];
  const float* bih    = (const float*)d_in[6];
  const float* bhh    = (const float*)d_in[7];
  const float* linW   = (const float*)d_in[8];
  const float* linb   = (const float*)d_in[9];
  const float* gamma  = (const float*)d_in[10];
  const float* beta   = (const float*)d_in[11];
  float* out = (float*)d_out;

  char* ws = (char*)d_ws;
  _Float16* Xf   = (_Float16*)(ws + 0);           //  32 MB
  _Float16* Hc0  = (_Float16*)(ws + 33554432);    //  32 MB
  _Float16* Hc1  = (_Float16*)(ws + 67108864);    //  32 MB
  _Float16* Gx   = (_Float16*)(ws + 100663296);   // 128 MB
  _Float16* Wihf = (_Float16*)(ws + 234881024);   //   4 MB
  _Float16* Whhf = (_Float16*)(ws + 239075328);   //   2 MB
  float*    bias = (float*)   (ws + 241172480);   //  16 KB
  _Float16* pub0 = (_Float16*)(ws + 241188864);   //  64 KB
  _Float16* pub1 = (_Float16*)(ws + 241254400);   //  64 KB
  unsigned int* flg = (unsigned int*)(ws + 241319936); // 16 KB (2 x 8KB)
  float*  logits = (float*)   (ws + 241336320);   // 128 KB
  if (ws_size < 241500000) return;

  hipMemsetAsync(Hc0, 0, 33554432, stream);
  hipMemsetAsync(Hc1, 0, 33554432, stream);
  hipMemsetAsync(flg, 0, 16384, stream);

  k_prep<<<4096, 256, 0, stream>>>(x, wih, whh, bih, bhh, Xf, Wihf, Whhf, bias);

  // layer 0
  k_gemm<<<dim3(256, 16), 256, 0, stream>>>(Xf, Wihf, bias, Gx);
  k_rec<<<32, 512, 0, stream>>>(Gx, Whhf, ln, Hc0, pub0, flg);
  // layer 1
  k_gemm<<<dim3(256, 16), 256, 0, stream>>>(Hc0, Wihf + 2*1024*512, bias + 2048, Gx);
  k_rec<<<32, 512, 0, stream>>>(Gx, Whhf + 2*1024*256, ln, Hc1, pub1, flg + 2048);

  k_head1<<<8192, 256, 0, stream>>>(Hc1, linW, linb, gamma, beta, out, logits);
  k_head2<<<32, 256, 0, stream>>>(logits, maskraw, out + 16777216);
}

// Round 14
// 5688.127 us; speedup vs baseline: 1.0184x; 1.0139x over previous
//
#include <hip/hip_runtime.h>
#include <stdint.h>

// ---------------------------------------------------------------------------
// BiLSTM (2 layers, B=32,T=1024,D=512,H=256) + linear/top2 + LayerNorm + mask
// r14 = r13 with ONE value-exact edit:
//   - k_rec: loop bound = max_len (max over the 32 sequence lengths) instead
//     of 1024. Recurrence is row-local and every valid output has
//     s < mylen[j] <= max_len, so truncation is bit-exact. All WGs compute
//     the identical bound -> protocol lockstep preserved.
// k_rec protocol / prep / gemm / heads / launch otherwise r13-verbatim.
// ---------------------------------------------------------------------------

typedef _Float16 half8 __attribute__((ext_vector_type(8)));
typedef _Float16 half4v __attribute__((ext_vector_type(4)));
typedef float f32x4 __attribute__((ext_vector_type(4)));
typedef unsigned int uint4v __attribute__((ext_vector_type(4)));
typedef unsigned int uint2v __attribute__((ext_vector_type(2)));

#define N_X    (32768*512)
#define N_WIH  (2*2*1024*512)
#define N_WHH  (2*2*1024*256)
#define N_BIAS (2*2*1024)

// direct global->LDS copy, 16B per lane (gfx950)
__device__ __forceinline__ void gload_lds16(const _Float16* g, _Float16* l) {
  __builtin_amdgcn_global_load_lds(
      (const __attribute__((address_space(1))) void*)g,
      (__attribute__((address_space(3))) void*)l, 16, 0, 0);
}

// ---------------------------------------------------------------- prep ------
__global__ __launch_bounds__(256) void k_prep(
    const float* __restrict__ x, const float* __restrict__ wih,
    const float* __restrict__ whh, const float* __restrict__ bih,
    const float* __restrict__ bhh, _Float16* __restrict__ xf,
    _Float16* __restrict__ wihf, _Float16* __restrict__ whhf,
    float* __restrict__ bias)
{
  const int total4 = (N_X + N_WIH + N_WHH + N_BIAS) >> 2;
  for (int i4 = blockIdx.x*256 + threadIdx.x; i4 < total4; i4 += gridDim.x*256) {
    int i = i4 << 2;
    if (i < N_X) {
      f32x4 v = *(const f32x4*)(x + i);
      half4v h;
#pragma unroll
      for (int j = 0; j < 4; ++j) h[j] = (_Float16)v[j];
      *(half4v*)(xf + i) = h;
    } else if (i < N_X + N_WIH) {
      int j0 = i - N_X;
      f32x4 v = *(const f32x4*)(wih + j0);
      half4v h;
#pragma unroll
      for (int j = 0; j < 4; ++j) h[j] = (_Float16)v[j];
      *(half4v*)(wihf + j0) = h;
    } else if (i < N_X + N_WIH + N_WHH) {
      int j0 = i - N_X - N_WIH;
      f32x4 v = *(const f32x4*)(whh + j0);
      half4v h;
#pragma unroll
      for (int j = 0; j < 4; ++j) h[j] = (_Float16)v[j];
      *(half4v*)(whhf + j0) = h;
    } else {
      int j0 = i - N_X - N_WIH - N_WHH;
      f32x4 a = *(const f32x4*)(bih + j0);
      f32x4 b = *(const f32x4*)(bhh + j0);
      f32x4 r;
#pragma unroll
      for (int j = 0; j < 4; ++j) r[j] = a[j] + b[j];
      *(f32x4*)(bias + j0) = r;
    }
  }
}

// ---------------------------------------------------------------- gemm ------
// C[32768][2048] = A[32768][512] @ Bw[2048][512]^T + bias, gate-interleaved C.
// 2-phase pipeline: stage tile k+1 (global_load_lds) BEFORE compute on tile k,
// ONE barrier per K-step (drains stage vmcnt + lgkm). Bit-identical C.
__global__ __launch_bounds__(256) void k_gemm(
    const _Float16* __restrict__ A, const _Float16* __restrict__ Bw,
    const float* __restrict__ bias, _Float16* __restrict__ C)
{
  __shared__ __align__(16) _Float16 As[2][128*32];
  __shared__ __align__(16) _Float16 Bs[2][128*32];
  const int ti = blockIdx.x, tj = blockIdx.y;
  const int tid = threadIdx.x, l = tid & 63, w = tid >> 6;
  const int wm = w >> 1, wn = w & 1;
  f32x4 acc[4][4] = {};

  // prologue: stage kk=0 into buffer 0
#pragma unroll
  for (int p = 0; p < 2; ++p) {
    int idx = p*256 + tid;
    int rr = idx >> 2, c = (idx & 3) * 8;
    gload_lds16(A + (size_t)(ti*128 + rr)*512 + c, As[0] + idx*8);
    gload_lds16(Bw + (size_t)(tj*128 + rr)*512 + c, Bs[0] + idx*8);
  }
  __syncthreads();   // drains vmcnt: buffer 0 ready

  int cur = 0;
  for (int kk = 0; kk < 512; kk += 32) {
    // stage next tile into the other buffer (overlaps with compute below)
    if (kk + 32 < 512) {
#pragma unroll
      for (int p = 0; p < 2; ++p) {
        int idx = p*256 + tid;
        int rr = idx >> 2, c = (idx & 3) * 8;
        gload_lds16(A + (size_t)(ti*128 + rr)*512 + kk + 32 + c, As[cur^1] + idx*8);
        gload_lds16(Bw + (size_t)(tj*128 + rr)*512 + kk + 32 + c, Bs[cur^1] + idx*8);
      }
    }
    // compute on current buffer (fragment layout/order identical to r11)
    half8 af[4], bfr[4];
#pragma unroll
    for (int m = 0; m < 4; ++m)
      af[m] = *(const half8*)(As[cur] + (wm*64 + m*16 + (l&15))*32 + (l>>4)*8);
#pragma unroll
    for (int n = 0; n < 4; ++n)
      bfr[n] = *(const half8*)(Bs[cur] + (wn*64 + n*16 + (l&15))*32 + (l>>4)*8);
#pragma unroll
    for (int m = 0; m < 4; ++m)
#pragma unroll
      for (int n = 0; n < 4; ++n)
        acc[m][n] = __builtin_amdgcn_mfma_f32_16x16x32_f16(af[m], bfr[n], acc[m][n], 0, 0, 0);
    __syncthreads();   // one barrier/K-step: stage drained, buffers safe
    cur ^= 1;
  }

  const int colb = tj*128 + wn*64 + (l & 15);
  const int rowb = ti*128 + wm*64 + ((l >> 4) << 2);
#pragma unroll
  for (int n = 0; n < 4; ++n) {
    int cg = colb + n*16;
    float bv = bias[cg];
    int dirb = cg >> 10, g = (cg >> 8) & 3, col = cg & 255;
    size_t nc = (size_t)dirb*1024 + col*4 + g;
#pragma unroll
    for (int m = 0; m < 4; ++m)
#pragma unroll
      for (int j = 0; j < 4; ++j)
        C[(size_t)(rowb + m*16 + j)*2048 + nc] = (_Float16)(acc[m][n][j] + bv);
  }
}

// ----------------------------------------------------------------- rec ------
__device__ __forceinline__ float sigf(float x) {
  return __fdividef(1.f, 1.f + __expf(-x));
}
__device__ __forceinline__ float tanh_fast(float x) {
  float e = __expf(-2.f * fabsf(x));
  float r = __fdividef(1.f - e, 1.f + e);
  return x < 0.f ? -r : r;
}

// grid = 32 WGs x 512 threads; workers have (bid&7) < 2: dir = bid&7, q = bid>>3.
// Wave w8 = rh*4 + colq: rows [rh*16, rh*16+16), cols [q*64+colq*16, +16).
// flags layout: flags[dir*128 + w8*16 + q] (u32). The 4 WG flags of (dir,w8)
// share one 16B quad -> single dwordx4 poll. xcd posts at flags[1024+wid].
// pub: [2 parity][2 dir][4 q][32][64] fp16 (r3-proven layout).
__global__ __launch_bounds__(512, 2) void k_rec(
    const _Float16* __restrict__ Gx,   // [32768][2048] gate-interleaved
    const _Float16* __restrict__ Whh,  // [2][1024][256]
    const long long* __restrict__ lens_raw,
    _Float16* __restrict__ Hout,       // [32768][512]  pre-zeroed
    _Float16* __restrict__ pub,        // [2 par][2 dir][4 q][32][64]
    unsigned int* __restrict__ flags)
{
  const int bid = blockIdx.x;
  const int sub = bid & 7;
  if (sub >= 2) return;
  const int dir = sub, q = bid >> 3;
  const int wid = dir*4 + q;
  const int tid = threadIdx.x, w8 = tid >> 6, l = tid & 63;
  const int lq = l >> 4;
  const int rh = w8 >> 2;            // row half 0/1
  const int colq = w8 & 3;           // col quarter 0..3
  const int ncl = colq*16 + (l & 15);  // col within WG's 64-col slice

  __shared__ __align__(16) _Float16 hbuf[2*32*256];  // 2 parity x 16KB
  __shared__ int s_fast;
  for (int i = tid; i < 2*32*256; i += 512) hbuf[i] = (_Float16)0.f;

  // ---- XCD placement handshake (once) ----
  int xcc;
  asm volatile("s_getreg_b32 %0, hwreg(HW_REG_XCC_ID)" : "=s"(xcc));
  unsigned int* xcdbuf = flags + 1024;
  if (tid == 0) {
    __hip_atomic_store(&xcdbuf[wid], (unsigned)(xcc + 1),
                       __ATOMIC_RELEASE, __HIP_MEMORY_SCOPE_AGENT);
    unsigned vv[4];
    for (int i = 0; i < 4; ++i) {
      unsigned u;
      do {
        u = __hip_atomic_load(&xcdbuf[dir*4 + i],
                              __ATOMIC_ACQUIRE, __HIP_MEMORY_SCOPE_AGENT);
      } while (u == 0);
      vv[i] = u;
    }
    s_fast = (vv[0]==vv[1] && vv[1]==vv[2] && vv[2]==vv[3]) ? 1 : 0;
  }

  // Whh B-fragments resident in registers: wave's 16 cols, all 4 gates.
  half8 Bf[4][8];
#pragma unroll
  for (int g = 0; g < 4; ++g)
#pragma unroll
    for (int kt = 0; kt < 8; ++kt)
      Bf[g][kt] = *(const half8*)(Whh + ((size_t)dir*1024 + g*256 + q*64 + ncl)*256 + kt*32 + lq*8);

  // lengths: int64/int32 detection (r5-proven), rows r(j) = rh*16 + lq*4 + j
  int mylen[4];
  int maxlen;
  {
    bool ok64 = true;
    for (int i = 0; i < 32; ++i) {
      long long vv = lens_raw[i];
      ok64 = ok64 && (vv >= 1 && vv <= 1024);
    }
    const int* l32 = (const int*)lens_raw;
#pragma unroll
    for (int j = 0; j < 4; ++j) {
      int idx = rh*16 + lq*4 + j;
      mylen[j] = ok64 ? (int)lens_raw[idx] : l32[idx];
    }
    int mx = 1;
    for (int i = 0; i < 32; ++i) {
      int v = ok64 ? (int)lens_raw[i] : l32[i];
      mx = v > mx ? v : mx;
    }
    maxlen = mx < 1 ? 1 : (mx > 1024 ? 1024 : mx);
  }

  float cst[4] = {};
  half4v gpf[4];

#pragma unroll
  for (int j = 0; j < 4; ++j) {
    int grow = rh*16 + lq*4 + j;
    int t = dir == 0 ? 0 : mylen[j] - 1;
    gpf[j] = *(const half4v*)(Gx + ((size_t)grow*1024 + t)*2048 + dir*1024 + ((q*64 + ncl) << 2));
  }

  // staging: 768 x 16B chunks (3 partners x 32 rows x 8 col-groups).
  // chunk c: i=c>>8 (partner), rr=(c&255)>>3 (row), cg=c&7 (8-half group).
  // thread stages c=tid, and (tid<256) c=tid+512 -> same (rr,cg), partner 2.
  int qp_[3];
#pragma unroll
  for (int i = 0; i < 3; ++i) qp_[i] = i + (i >= q ? 1 : 0);
  const int c1  = tid;
  const int i1  = c1 >> 8;                 // 0 or 1
  const int rr  = (c1 & 255) >> 3;         // 0..31
  const int cg  = c1 & 7;                  // 0..7
  const int w8p = ((c1 & 255) >> 7)*4 + (cg >> 1);   // producer wave
  const int qpa = qp_[i1];
  const int qpb = qp_[2];
  const bool two = (tid < 256);
  // poll quad: 4 WG flags of (dir, w8p)
  const volatile uint4v* fquad =
      (const volatile uint4v*)(flags + dir*128 + w8p*16);
  // LDS dst bytes (XOR swizzle acts on 16B granules -> block copy valid)
  const int dsta = ((rr*512 + (qpa*64 + cg*8)*2) ^ ((rr & 7) << 4));
  const int dstb = ((rr*512 + (qpb*64 + cg*8)*2) ^ ((rr & 7) << 4));

  __syncthreads();
  const bool FAST = (s_fast != 0);

  for (int s = 0; s < maxlen; ++s) {
    const int p = s & 1;
    const int pr_base = p * 16384;       // byte offsets into hbuf
    const int pw_base = (p ^ 1) * 16384;

    // ---- compute phase at elevated priority (pure scheduler hint) ----
    __builtin_amdgcn_s_setprio(1);

    // gates: acc init from Gx, then 8 kt MFMAs  (r5-verbatim summation order)
    f32x4 acc[4];
#pragma unroll
    for (int g = 0; g < 4; ++g)
#pragma unroll
      for (int j = 0; j < 4; ++j) acc[g][j] = (float)gpf[j][g];

    // prefetch step s+1 (r5-verbatim position + clamped formula)
#pragma unroll
    for (int j = 0; j < 4; ++j) {
      int grow = rh*16 + lq*4 + j;
      int t = dir == 0 ? s + 1 : mylen[j] - 2 - s;
      t = t < 0 ? 0 : (t > 1023 ? 1023 : t);
      gpf[j] = *(const half4v*)(Gx + ((size_t)grow*1024 + t)*2048 + dir*1024 + ((q*64 + ncl) << 2));
    }

    // gates += h(s-1) @ Whh^T  (A rows = wave's 16 batch rows from LDS)
#pragma unroll
    for (int kt = 0; kt < 8; ++kt) {
      int row = rh*16 + (l & 15);
      int byte = pr_base + ((row*512 + kt*64 + lq*16) ^ ((row & 7) << 4));
      half8 a = *(const half8*)((const char*)hbuf + byte);
#pragma unroll
      for (int g = 0; g < 4; ++g)
        acc[g] = __builtin_amdgcn_mfma_f32_16x16x32_f16(a, Bf[g][kt], acc[g], 0, 0, 0);
    }

    // activation: 4 cells; LDS write + pub publish + Hout (r5-verbatim)
    _Float16* mypub = pub + ((size_t)p*8 + wid)*2048;
#pragma unroll
    for (int j = 0; j < 4; ++j) {
      float gi = sigf(acc[0][j]);
      float gf = sigf(acc[1][j]);
      float gg = tanh_fast(acc[2][j]);
      float go = sigf(acc[3][j]);
      float cn = gf*cst[j] + gi*gg;
      cst[j] = cn;
      float hn = go * tanh_fast(cn);
      _Float16 h16 = (_Float16)hn;
      int r = rh*16 + lq*4 + j;
      int colg = q*64 + ncl;
      int byte = pw_base + ((r*512 + colg*2) ^ ((r & 7) << 4));
      *(_Float16*)((char*)hbuf + byte) = h16;   // own slice for next step
      mypub[r*64 + ncl] = h16;                  // publish
      if (s < mylen[j]) {
        int t = dir == 0 ? s : mylen[j] - 1 - s;
        Hout[((size_t)r*1024 + t)*512 + dir*256 + colg] = h16;
      }
    }

    __builtin_amdgcn_s_setprio(0);   // drain/flag/poll/stage at normal prio

    if (FAST) {
      // same-XCD: shared L2 is the coherence point (r5-proven sequence)
      asm volatile("s_waitcnt vmcnt(0)" ::: "memory");
      if (l == 0) flags[dir*128 + w8*16 + q] = (unsigned)(s + 1);  // plain store
      asm volatile("" ::: "memory");
      // poll: ONE volatile dwordx4 covering all 4 WG flags of (dir, w8p)
      int guard = 0;
      unsigned mn;
      do {
        uint4v f = *fquad;
        unsigned a = f[0] < f[1] ? f[0] : f[1];
        unsigned b = f[2] < f[3] ? f[2] : f[3];
        mn = a < b ? a : b;
        if (++guard > (1 << 22)) break;
      } while (mn <= (unsigned)s);
      // stage 16B chunks (volatile = L1-bypass; <=2 serialized round-trips)
      {
        const volatile uint4v* spa =
            (const volatile uint4v*)(pub + ((size_t)p*8 + dir*4 + qpa)*2048 + rr*64 + cg*8);
        uint4v da = *spa;
        *(uint4v*)((char*)hbuf + pw_base + dsta) = da;
        if (two) {
          const volatile uint4v* spb =
              (const volatile uint4v*)(pub + ((size_t)p*8 + dir*4 + qpb)*2048 + rr*64 + cg*8);
          uint4v db = *spb;
          *(uint4v*)((char*)hbuf + pw_base + dstb) = db;
        }
      }
    } else {
      // cross-XCD fallback (r5 fence pattern, new addresses)
      __threadfence();
      if (l == 0)
        __hip_atomic_store(&flags[dir*128 + w8*16 + q], (unsigned)(s + 1),
                           __ATOMIC_RELAXED, __HIP_MEMORY_SCOPE_AGENT);
      unsigned f0, f1, f2;
      int guard = 0;
      const unsigned* fb = flags + dir*128 + w8p*16;
      do {
        f0 = __hip_atomic_load(fb + qp_[0], __ATOMIC_RELAXED, __HIP_MEMORY_SCOPE_AGENT);
        f1 = __hip_atomic_load(fb + qp_[1], __ATOMIC_RELAXED, __HIP_MEMORY_SCOPE_AGENT);
        f2 = __hip_atomic_load(fb + qp_[2], __ATOMIC_RELAXED, __HIP_MEMORY_SCOPE_AGENT);
        if (++guard > (1 << 22)) break;
      } while (f0 <= (unsigned)s || f1 <= (unsigned)s || f2 <= (unsigned)s);
      __threadfence();
      {
        uint4v da = *(const uint4v*)(pub + ((size_t)p*8 + dir*4 + qpa)*2048 + rr*64 + cg*8);
        *(uint4v*)((char*)hbuf + pw_base + dsta) = da;
        if (two) {
          uint4v db = *(const uint4v*)(pub + ((size_t)p*8 + dir*4 + qpb)*2048 + rr*64 + cg*8);
          *(uint4v*)((char*)hbuf + pw_base + dstb) = db;
        }
      }
    }
    __syncthreads();
  }
}

// ---------------------------------------------------------------- head ------
__global__ __launch_bounds__(256) void k_head1(
    const _Float16* __restrict__ H, const float* __restrict__ linW,
    const float* __restrict__ linb, const float* __restrict__ gamma,
    const float* __restrict__ beta, float* __restrict__ lnout,
    float* __restrict__ logits)
{
  const int r = blockIdx.x*4 + (threadIdx.x >> 6);
  const int l = threadIdx.x & 63;
  half8 hv = *(const half8*)(H + (size_t)r*512 + l*8);
  f32x4 wa = *(const f32x4*)(linW + l*8);
  f32x4 wb = *(const f32x4*)(linW + l*8 + 4);
  float x[8], wv[8];
#pragma unroll
  for (int j = 0; j < 8; ++j) x[j] = (float)hv[j];
#pragma unroll
  for (int j = 0; j < 4; ++j) { wv[j] = wa[j]; wv[j+4] = wb[j]; }
  float s1 = 0.f, s2 = 0.f, sd = 0.f;
#pragma unroll
  for (int j = 0; j < 8; ++j) { s1 += x[j]; s2 += x[j]*x[j]; sd += x[j]*wv[j]; }
#pragma unroll
  for (int off = 32; off >= 1; off >>= 1) {
    s1 += __shfl_xor(s1, off);
    s2 += __shfl_xor(s2, off);
    sd += __shfl_xor(sd, off);
  }
  float mu = s1 * (1.f/512.f);
  float var = s2 * (1.f/512.f) - mu*mu;
  var = var < 0.f ? 0.f : var;
  float rstd = rsqrtf(var + 1e-5f);
  f32x4 ga = *(const f32x4*)(gamma + l*8);
  f32x4 gb = *(const f32x4*)(gamma + l*8 + 4);
  f32x4 ba = *(const f32x4*)(beta + l*8);
  f32x4 bb = *(const f32x4*)(beta + l*8 + 4);
  f32x4 oa, ob;
#pragma unroll
  for (int j = 0; j < 4; ++j) {
    oa[j] = (x[j]   - mu)*rstd*ga[j] + ba[j];
    ob[j] = (x[j+4] - mu)*rstd*gb[j] + bb[j];
  }
  *(f32x4*)(lnout + (size_t)r*512 + l*8) = oa;
  *(f32x4*)(lnout + (size_t)r*512 + l*8 + 4) = ob;
  if (l == 0) logits[r] = sd + linb[0];
}

__global__ __launch_bounds__(256) void k_head2(
    const float* __restrict__ logits, const void* __restrict__ maskraw,
    float* __restrict__ outmask)
{
  __shared__ float swv[4];
  __shared__ int   swi[4];
  __shared__ int   sidx[2];
  const int b = blockIdx.x, tid = threadIdx.x;
  const float* lg = logits + b*1024;
  float lv[4]; int ltt[4];
#pragma unroll
  for (int i = 0; i < 4; ++i) { ltt[i] = tid + i*256; lv[i] = lg[ltt[i]]; }
  int excl = -1;
  for (int pass = 0; pass < 2; ++pass) {
    float bv = 3.0e38f; int bi = 1 << 30;
#pragma unroll
    for (int i = 0; i < 4; ++i)
      if (ltt[i] != excl && (lv[i] < bv || (lv[i] == bv && ltt[i] < bi))) { bv = lv[i]; bi = ltt[i]; }
#pragma unroll
    for (int off = 32; off >= 1; off >>= 1) {
      float ov = __shfl_xor(bv, off); int oi = __shfl_xor(bi, off);
      if (ov < bv || (ov == bv && oi < bi)) { bv = ov; bi = oi; }
    }
    if ((tid & 63) == 0) { swv[tid >> 6] = bv; swi[tid >> 6] = bi; }
    __syncthreads();
    if (tid == 0) {
      float fv = swv[0]; int fi = swi[0];
      for (int u = 1; u < 4; ++u)
        if (swv[u] < fv || (swv[u] == fv && swi[u] < fi)) { fv = swv[u]; fi = swi[u]; }
      sidx[pass] = fi;
    }
    __syncthreads();
    excl = sidx[0];
    __syncthreads();
  }
  const int i1 = sidx[0], i2 = sidx[1];
  const unsigned char* mb = (const unsigned char*)maskraw;
  const bool mode8 = mb[1] != 0;
#pragma unroll
  for (int i = 0; i < 4; ++i) {
    int t = tid + i*256;
    bool mv = mode8 ? (mb[b*1024 + t] != 0)
                    : (((const int*)maskraw)[b*1024 + t] != 0);
    outmask[b*1024 + t] = (mv && t != i1 && t != i2) ? 1.f : 0.f;
  }
}

// --------------------------------------------------------------- launch -----
extern "C" void kernel_launch(void* const* d_in, const int* in_sizes, int n_in,
                              void* d_out, int out_size, void* d_ws, size_t ws_size,
                              hipStream_t stream) {
  const float* x      = (const float*)d_in[0];
  const long long* ln = (const long long*)d_in[1];
  const void* maskraw = d_in[3];
  const float* wih    = (const float*)d_in[4];
  const float* whh    = (const float*)d_in[5];
  const float* bih    = (const float*)d_in[6];
  const float* bhh    = (const float*)d_in[7];
  const float* linW   = (const float*)d_in[8];
  const float* linb   = (const float*)d_in[9];
  const float* gamma  = (const float*)d_in[10];
  const float* beta   = (const float*)d_in[11];
  float* out = (float*)d_out;

  char* ws = (char*)d_ws;
  _Float16* Xf   = (_Float16*)(ws + 0);           //  32 MB
  _Float16* Hc0  = (_Float16*)(ws + 33554432);    //  32 MB
  _Float16* Hc1  = (_Float16*)(ws + 67108864);    //  32 MB
  _Float16* Gx   = (_Float16*)(ws + 100663296);   // 128 MB
  _Float16* Wihf = (_Float16*)(ws + 234881024);   //   4 MB
  _Float16* Whhf = (_Float16*)(ws + 239075328);   //   2 MB
  float*    bias = (float*)   (ws + 241172480);   //  16 KB
  _Float16* pub0 = (_Float16*)(ws + 241188864);   //  64 KB
  _Float16* pub1 = (_Float16*)(ws + 241254400);   //  64 KB
  unsigned int* flg = (unsigned int*)(ws + 241319936); // 16 KB (2 x 8KB)
  float*  logits = (float*)   (ws + 241336320);   // 128 KB
  if (ws_size < 241500000) return;

  hipMemsetAsync(Hc0, 0, 33554432, stream);
  hipMemsetAsync(Hc1, 0, 33554432, stream);
  hipMemsetAsync(flg, 0, 16384, stream);

  k_prep<<<4096, 256, 0, stream>>>(x, wih, whh, bih, bhh, Xf, Wihf, Whhf, bias);

  // layer 0
  k_gemm<<<dim3(256, 16), 256, 0, stream>>>(Xf, Wihf, bias, Gx);
  k_rec<<<32, 512, 0, stream>>>(Gx, Whhf, ln, Hc0, pub0, flg);
  // layer 1
  k_gemm<<<dim3(256, 16), 256, 0, stream>>>(Hc0, Wihf + 2*1024*512, bias + 2048, Gx);
  k_rec<<<32, 512, 0, stream>>>(Gx, Whhf + 2*1024*256, ln, Hc1, pub1, flg + 2048);

  k_head1<<<8192, 256, 0, stream>>>(Hc1, linW, linb, gamma, beta, out, logits);
  k_head2<<<32, 256, 0, stream>>>(logits, maskraw, out + 16777216);
}